// Round 2
// baseline (277.289 us; speedup 1.0000x reference)
//
#include <hip/hip_runtime.h>

#define CDIM 512
#define NH 8
#define HWDIM 4096

// Fold weights: wvT[c*8+n] = sum_j wqkv[(1024+64n+j)*512 + c]
//               wp [o*8+n] = sum_j wproj[o*512 + 64n + j]
__global__ __launch_bounds__(256) void prep_kernel(
    const float* __restrict__ wqkv, const float* __restrict__ wproj,
    float* __restrict__ wvT, float* __restrict__ wp) {
  int idx = blockIdx.x * 256 + threadIdx.x;
  if (idx < 4096) {
    int c = idx >> 3, n = idx & 7;
    const float* p = wqkv + (size_t)(1024 + n * 64) * CDIM + c;
    float s = 0.f;
#pragma unroll 8
    for (int j = 0; j < 64; ++j) s += p[(size_t)j * CDIM];
    wvT[idx] = s;
  } else if (idx < 8192) {
    int i2 = idx - 4096;
    int o = i2 >> 3, n = i2 & 7;
    const float* p = wproj + (size_t)o * CDIM + n * 64;
    float s = 0.f;
#pragma unroll 8
    for (int j = 0; j < 64; ++j) s += p[j];
    wp[i2] = s;
  }
}

// Stage A: S[b][n][hw] = sum_c wvT[c][n] * x[b][c][hw]
// Pure read-stream: 128 MB read, 2 MB write.
// Block: 256 thr = 8 channel-groups (64 ch each) x 32 float4-slots (128 positions).
// Grid: 16 b x 32 windows = 512 blocks.
__global__ __launch_bounds__(256) void s_kernel(
    const float* __restrict__ x, const float* __restrict__ wvT,
    float* __restrict__ S) {
  __shared__ __align__(16) float sWv[4096];                 // [c][n]
  __shared__ __align__(16) float sPart[NH][8][32][4];       // [n][cg][slot][p] 32 KB

  const int t = threadIdx.x;
  for (int i = t; i < 4096; i += 256) sWv[i] = wvT[i];
  __syncthreads();

  const int cg = t >> 5;        // 0..7 : channel group (64 channels)
  const int slot = t & 31;      // 0..31: float4 slot within 128-position window
  const int wb = blockIdx.x;
  const int b = wb >> 5;
  const int hw0 = (wb & 31) * 128;
  const float* xb = x + ((size_t)b * CDIM) * HWDIM + hw0 + slot * 4;

  float acc[NH][4];
#pragma unroll
  for (int n = 0; n < NH; ++n) { acc[n][0] = acc[n][1] = acc[n][2] = acc[n][3] = 0.f; }

  const int c0 = cg * 64;
  for (int g = 0; g < 8; ++g) {
    // 8 loads issued back-to-back -> 8 outstanding per thread
    float4 xv[8];
#pragma unroll
    for (int j = 0; j < 8; ++j)
      xv[j] = *(const float4*)(xb + (size_t)(c0 + g * 8 + j) * HWDIM);
#pragma unroll
    for (int j = 0; j < 8; ++j) {
      const int c = c0 + g * 8 + j;
      const float4 w0 = *(const float4*)&sWv[c * 8];
      const float4 w1 = *(const float4*)&sWv[c * 8 + 4];
      const float wn[8] = {w0.x, w0.y, w0.z, w0.w, w1.x, w1.y, w1.z, w1.w};
      const float xr[4] = {xv[j].x, xv[j].y, xv[j].z, xv[j].w};
#pragma unroll
      for (int n = 0; n < NH; ++n) {
#pragma unroll
        for (int p = 0; p < 4; ++p) acc[n][p] = fmaf(wn[n], xr[p], acc[n][p]);
      }
    }
  }

#pragma unroll
  for (int n = 0; n < NH; ++n)
    *(float4*)&sPart[n][cg][slot][0] = make_float4(acc[n][0], acc[n][1], acc[n][2], acc[n][3]);
  __syncthreads();

  // reduce across 8 channel groups; thread r: n2 = r>>5 (0..7), slot2 = r&31
  const int n2 = t >> 5;
  const int slot2 = t & 31;
  float4 sum = make_float4(0.f, 0.f, 0.f, 0.f);
#pragma unroll
  for (int g = 0; g < 8; ++g) {
    const float4 a = *(const float4*)&sPart[n2][g][slot2][0];
    sum.x += a.x; sum.y += a.y; sum.z += a.z; sum.w += a.w;
  }
  *(float4*)&S[((size_t)b * NH + n2) * HWDIM + hw0 + slot2 * 4] = sum;
}

// Stage B: y[b][o][hw] = bias[o] + sum_n wp[o][n] * S[b][n][hw]
// Pure write-stream: 128 MB contiguous writes, ~2 MB cached reads.
// Block: 256 thr, each owns one float4 of hw (1024-position span).
// Grid: 16 b x 4 spans x 8 o-groups = 512 blocks; block writes 64 rows x 4 KB.
__global__ __launch_bounds__(256) void y_kernel(
    const float* __restrict__ S, const float* __restrict__ wp,
    const float* __restrict__ bias, float* __restrict__ y) {
  __shared__ __align__(16) float sWp[4096];   // [o][n]
  __shared__ __align__(16) float sB[512];

  const int t = threadIdx.x;
  for (int i = t; i < 4096; i += 256) sWp[i] = wp[i];
  for (int i = t; i < 512; i += 256) sB[i] = bias[i];
  __syncthreads();

  const int wb = blockIdx.x;
  const int b = wb >> 5;            // 0..15
  const int span = (wb >> 3) & 3;   // 0..3  : 1024-position span
  const int og = wb & 7;            // 0..7  : 64-output group
  const int hwo = span * 1024 + t * 4;

  // pin S[b][n][hwo..hwo+4) in registers
  float s[NH][4];
#pragma unroll
  for (int n = 0; n < NH; ++n) {
    const float4 a = *(const float4*)&S[((size_t)b * NH + n) * HWDIM + hwo];
    s[n][0] = a.x; s[n][1] = a.y; s[n][2] = a.z; s[n][3] = a.w;
  }

  float* yb = y + ((size_t)b * CDIM) * HWDIM + hwo;
  const int o0 = og * 64;
#pragma unroll 4
  for (int oo = 0; oo < 64; ++oo) {
    const int o = o0 + oo;
    const float4 w0 = *(const float4*)&sWp[o * 8];
    const float4 w1 = *(const float4*)&sWp[o * 8 + 4];
    const float wn[8] = {w0.x, w0.y, w0.z, w0.w, w1.x, w1.y, w1.z, w1.w};
    const float bb = sB[o];
    float r[4] = {bb, bb, bb, bb};
#pragma unroll
    for (int n = 0; n < NH; ++n) {
#pragma unroll
      for (int p = 0; p < 4; ++p) r[p] = fmaf(wn[n], s[n][p], r[p]);
    }
    *(float4*)(yb + (size_t)o * HWDIM) = make_float4(r[0], r[1], r[2], r[3]);
  }
}

extern "C" void kernel_launch(void* const* d_in, const int* in_sizes, int n_in,
                              void* d_out, int out_size, void* d_ws, size_t ws_size,
                              hipStream_t stream) {
  const float* x     = (const float*)d_in[0];
  const float* wqkv  = (const float*)d_in[1];
  const float* wproj = (const float*)d_in[2];
  const float* bproj = (const float*)d_in[3];
  float* y = (float*)d_out;

  float* wvT = (float*)d_ws;        // 4096 floats
  float* wp  = wvT + 4096;          // 4096 floats
  float* S   = wp  + 4096;          // 16*8*4096 = 524288 floats (2 MB)

  prep_kernel<<<32, 256, 0, stream>>>(wqkv, wproj, wvT, wp);
  s_kernel<<<512, 256, 0, stream>>>(x, wvT, S);
  y_kernel<<<512, 256, 0, stream>>>(S, wp, bproj, y);
}

// Round 4
// 248.270 us; speedup vs baseline: 1.1169x; 1.1169x over previous
//
#include <hip/hip_runtime.h>

#define CDIM 512
#define NH 8
#define HWDIM 4096
#define TILE 128   // spatial positions per block
#define NT 512     // threads per block = 8 waves

typedef float f32x2 __attribute__((ext_vector_type(2)));

// Fold weights: wvT[c*8+n] = sum_j wqkv[(1024+64n+j)*512 + c]
//               wp [o*8+n] = sum_j wproj[o*512 + 64n + j]
__global__ __launch_bounds__(256) void prep_kernel(
    const float* __restrict__ wqkv, const float* __restrict__ wproj,
    float* __restrict__ wvT, float* __restrict__ wp) {
  int idx = blockIdx.x * 256 + threadIdx.x;
  if (idx < 4096) {
    int c = idx >> 3, n = idx & 7;
    const float* p = wqkv + (size_t)(1024 + n * 64) * CDIM + c;
    float s = 0.f;
#pragma unroll 8
    for (int j = 0; j < 64; ++j) s += p[(size_t)j * CDIM];
    wvT[idx] = s;
  } else if (idx < 8192) {
    int i2 = idx - 4096;
    int o = i2 >> 3, n = i2 & 7;
    const float* p = wproj + (size_t)o * CDIM + n * 64;
    float s = 0.f;
#pragma unroll 8
    for (int j = 0; j < 64; ++j) s += p[j];
    wp[i2] = s;
  }
}

// y[b,o,s] = bias[o] + sum_n wp[o,n] * (sum_c wvT[c,n] * x[b,c,s])
// 8 waves: phase 1 splits 512 channels 64/wave; phase 2 splits 512 outputs 64/wave.
// Lane owns 2 consecutive spatial positions (float2 loads, nt float2 stores).
// y stores are NON-TEMPORAL: keep x LLC-resident (x=128MB fits in 256MB L3;
// write-allocate of y was evicting half of x -> FETCH_SIZE 66MB -> HBM-latency reads).
__global__ __launch_bounds__(NT, 4) void fused_kernel(
    const float* __restrict__ x, const float* __restrict__ bias,
    const float* __restrict__ wvT, const float* __restrict__ wp,
    float* __restrict__ y) {
  __shared__ __align__(16) float sWv[4096];            // [c][n]
  __shared__ __align__(16) float sWp[4096];            // [o][n]
  __shared__ __align__(16) float sB[512];
  __shared__ __align__(16) float sS[8][NH][TILE];      // per-wave partial S (32 KB)

  const int t = threadIdx.x;
  for (int i = t; i < 4096; i += NT) { sWv[i] = wvT[i]; sWp[i] = wp[i]; }
  if (t < 512) sB[t] = bias[t];
  __syncthreads();

  const int wave = t >> 6;
  const int lane = t & 63;
  const int pos0 = blockIdx.x * TILE;        // 128 | 4096 so blocks never straddle b
  const int b = pos0 >> 12;
  const int hw0 = pos0 & (HWDIM - 1);
  const float* xb = x + ((size_t)b * CDIM) * HWDIM + hw0 + lane * 2;

  // ---- phase 1: S[n, pos] partials; wave handles 64 channels ----
  float acc[NH][2];
#pragma unroll
  for (int n = 0; n < NH; ++n) { acc[n][0] = 0.f; acc[n][1] = 0.f; }

  const int c0 = wave * 64;
#pragma unroll 8
  for (int cc = 0; cc < 64; ++cc) {
    const int c = c0 + cc;
    const float2 xv = *(const float2*)(xb + (size_t)c * HWDIM);
    const float4 w0 = *(const float4*)&sWv[c * 8];
    const float4 w1 = *(const float4*)&sWv[c * 8 + 4];
    const float wn[8] = {w0.x, w0.y, w0.z, w0.w, w1.x, w1.y, w1.z, w1.w};
#pragma unroll
    for (int n = 0; n < NH; ++n) {
      acc[n][0] = fmaf(wn[n], xv.x, acc[n][0]);
      acc[n][1] = fmaf(wn[n], xv.y, acc[n][1]);
    }
  }

#pragma unroll
  for (int n = 0; n < NH; ++n) {
    *(float2*)&sS[wave][n][lane * 2] = make_float2(acc[n][0], acc[n][1]);
  }
  __syncthreads();

  // ---- phase 2: reduce S across 8 waves, expand to 512 outputs ----
  float S2[NH][2];
#pragma unroll
  for (int n = 0; n < NH; ++n) {
    float s0 = 0.f, s1 = 0.f;
#pragma unroll
    for (int w = 0; w < 8; ++w) {
      const float2 a = *(const float2*)&sS[w][n][lane * 2];
      s0 += a.x; s1 += a.y;
    }
    S2[n][0] = s0; S2[n][1] = s1;
  }

  float* yb = y + ((size_t)b * CDIM) * HWDIM + hw0 + lane * 2;
  const int o0 = wave * 64;
#pragma unroll 4
  for (int oo = 0; oo < 64; ++oo) {
    const int o = o0 + oo;
    const float4 w0 = *(const float4*)&sWp[o * 8];
    const float4 w1 = *(const float4*)&sWp[o * 8 + 4];
    const float wn[8] = {w0.x, w0.y, w0.z, w0.w, w1.x, w1.y, w1.z, w1.w};
    const float bb = sB[o];
    float r0 = bb, r1 = bb;
#pragma unroll
    for (int n = 0; n < NH; ++n) {
      r0 = fmaf(wn[n], S2[n][0], r0);
      r1 = fmaf(wn[n], S2[n][1], r1);
    }
    f32x2 out;
    out.x = r0; out.y = r1;
    __builtin_nontemporal_store(out, (f32x2*)(yb + (size_t)o * HWDIM));
  }
}

extern "C" void kernel_launch(void* const* d_in, const int* in_sizes, int n_in,
                              void* d_out, int out_size, void* d_ws, size_t ws_size,
                              hipStream_t stream) {
  const float* x     = (const float*)d_in[0];
  const float* wqkv  = (const float*)d_in[1];
  const float* wproj = (const float*)d_in[2];
  const float* bproj = (const float*)d_in[3];
  float* y = (float*)d_out;

  float* wvT = (float*)d_ws;        // 4096 floats
  float* wp  = wvT + 4096;          // 4096 floats (32 KB total scratch)

  prep_kernel<<<32, 256, 0, stream>>>(wqkv, wproj, wvT, wp);
  fused_kernel<<<HWDIM * 16 / TILE, NT, 0, stream>>>(x, bproj, wvT, wp, y);
}